// Round 10
// baseline (89.293 us; speedup 1.0000x reference)
//
#include <hip/hip_runtime.h>
#include <hip/hip_bf16.h>

// SelfAttentionHead: EMB=1024, KEY=HEAD=64, B=4, T=4096
#define EMB 1024
#define NB  4
#define TT  4096
#define DD  64

// fold 1/sqrt(64) and log2(e) into Q so softmax runs in exp2 domain
static constexpr float SCALE2 = 0.125f * 1.4426950408889634f;

typedef __bf16          bfrag    __attribute__((ext_vector_type(8)));
typedef float           f32x4    __attribute__((ext_vector_type(4)));
typedef unsigned short  ushort8t __attribute__((ext_vector_type(8)));
typedef unsigned short  ushort4t __attribute__((ext_vector_type(4)));
typedef unsigned int    uint32;
typedef uint32          uint32x4 __attribute__((ext_vector_type(4)));

__device__ __forceinline__ unsigned short f2bf(float f) {
    __hip_bfloat16 h = __float2bfloat16(f);   // RNE
    return __builtin_bit_cast(unsigned short, h);
}
__device__ __forceinline__ float bf2f(unsigned short u) {
    uint32 v = ((uint32)u) << 16;
    return __builtin_bit_cast(float, v);
}
__device__ __forceinline__ uint32 pk2(float a, float b) {
    return (uint32)f2bf(a) | ((uint32)f2bf(b) << 16);
}

// ---------------------------------------------------------------------------
// Prep: Wt[n][k] bf16, n in [0,192) = concat(Wk, Wq*SCALE2, Wv) columns.
// ---------------------------------------------------------------------------
__global__ __launch_bounds__(256) void prep_wt(
    const float* __restrict__ Wk, const float* __restrict__ Wq,
    const float* __restrict__ Wv, unsigned short* __restrict__ Wt)
{
    const int o = blockIdx.x * 256 + threadIdx.x;   // 0 .. 192*1024-1
    const int n = o >> 10, k = o & 1023;
    float v;
    if (n < 64)       v = Wk[k * 64 + n];
    else if (n < 128) v = Wq[k * 64 + (n - 64)] * SCALE2;
    else              v = Wv[k * 64 + (n - 128)];
    Wt[o] = f2bf(v);
}

// ---------------------------------------------------------------------------
// QKV projection (round-4/8 proven, reverted from r9's M32 regression):
// bf16 MFMA GEMM, M-tile 64, 256 thr (4 waves), T14 reg-prefetch of next
// k-step's emb/W tiles. Outputs Q/K bf16 row-major (Q pre-scaled),
// V^T [b][h][t].
// ---------------------------------------------------------------------------
#define PSTR 66

__global__ __launch_bounds__(256) void qkv_mfma(
    const float* __restrict__ emb,
    const unsigned short* __restrict__ Wt,
    const float* __restrict__ bk, const float* __restrict__ bq,
    const float* __restrict__ bv,
    unsigned short* __restrict__ Qb, unsigned short* __restrict__ Kb,
    unsigned short* __restrict__ Vt)
{
    __shared__ unsigned short elds[64 * PSTR];
    __shared__ unsigned short wlds[192 * PSTR];

    const int tid = threadIdx.x;
    const int w = tid >> 6, l = tid & 63;
    const int lr = l & 15, lg = l >> 4;
    const int m0 = blockIdx.x * 64;

    f32x4 acc[12];
#pragma unroll
    for (int i = 0; i < 12; ++i) acc[i] = (f32x4){0.f, 0.f, 0.f, 0.f};

    const int er = tid >> 2, ec = (tid & 3) * 16;

    float4 f0, f1, f2, f3;
    ushort8t wr[6];
    {   // prologue: load k0 = 0 tiles into regs
        const float* src = emb + (size_t)(m0 + er) * EMB + ec;
        f0 = *(const float4*)(src + 0);
        f1 = *(const float4*)(src + 4);
        f2 = *(const float4*)(src + 8);
        f3 = *(const float4*)(src + 12);
#pragma unroll
        for (int i = 0; i < 6; ++i) {
            const int idx = tid + i * 256;
            const int row = idx >> 3, c = (idx & 7) * 8;
            wr[i] = *(const ushort8t*)&Wt[(size_t)row * 1024 + c];
        }
    }

    for (int it = 0; it < 16; ++it) {
        __syncthreads();   // previous iteration's MFMA reads are done
        {   // write staged regs -> LDS (f32 -> bf16 for emb)
            ushort8t lo, hi;
            lo[0]=f2bf(f0.x); lo[1]=f2bf(f0.y); lo[2]=f2bf(f0.z); lo[3]=f2bf(f0.w);
            lo[4]=f2bf(f1.x); lo[5]=f2bf(f1.y); lo[6]=f2bf(f1.z); lo[7]=f2bf(f1.w);
            hi[0]=f2bf(f2.x); hi[1]=f2bf(f2.y); hi[2]=f2bf(f2.z); hi[3]=f2bf(f2.w);
            hi[4]=f2bf(f3.x); hi[5]=f2bf(f3.y); hi[6]=f2bf(f3.z); hi[7]=f2bf(f3.w);
            *(ushort8t*)&elds[er * PSTR + ec]     = lo;
            *(ushort8t*)&elds[er * PSTR + ec + 8] = hi;
#pragma unroll
            for (int i = 0; i < 6; ++i) {
                const int idx = tid + i * 256;
                const int row = idx >> 3, c = (idx & 7) * 8;
                *(ushort8t*)&wlds[row * PSTR + c] = wr[i];
            }
        }
        // prefetch next k-step into regs (completes under the MFMA phase)
        if (it < 15) {
            const int kn = (it + 1) * 64;
            const float* src = emb + (size_t)(m0 + er) * EMB + kn + ec;
            f0 = *(const float4*)(src + 0);
            f1 = *(const float4*)(src + 4);
            f2 = *(const float4*)(src + 8);
            f3 = *(const float4*)(src + 12);
#pragma unroll
            for (int i = 0; i < 6; ++i) {
                const int idx = tid + i * 256;
                const int row = idx >> 3, c = (idx & 7) * 8;
                wr[i] = *(const ushort8t*)&Wt[(size_t)row * 1024 + kn + c];
            }
        }
        __syncthreads();
#pragma unroll
        for (int c = 0; c < 2; ++c) {
            bfrag a = *(const bfrag*)&elds[(w * 16 + lr) * PSTR + c * 32 + lg * 8];
#pragma unroll
            for (int nt = 0; nt < 12; ++nt) {
                bfrag bb = *(const bfrag*)&wlds[(nt * 16 + lr) * PSTR + c * 32 + lg * 8];
                acc[nt] = __builtin_amdgcn_mfma_f32_16x16x32_bf16(a, bb, acc[nt], 0, 0, 0);
            }
        }
    }

    const int rbase = m0 + w * 16 + lg * 4;
#pragma unroll
    for (int nt = 0; nt < 12; ++nt) {
        const int n = nt * 16 + lr;
        float bias;
        if (n < 64)       bias = bk[n];
        else if (n < 128) bias = bq[n - 64] * SCALE2;
        else              bias = bv[n - 128];
        if (nt < 8) {
            unsigned short* dst = (nt < 4) ? Kb : Qb;
            const int d = (nt < 4) ? n : (n - 64);
#pragma unroll
            for (int rg = 0; rg < 4; ++rg)
                dst[(size_t)(rbase + rg) * 64 + d] = f2bf(acc[nt][rg] + bias);
        } else {
            const int h = n - 128;
            const int b = rbase >> 12, t = rbase & (TT - 1);
            ushort4t pk;
#pragma unroll
            for (int rg = 0; rg < 4; ++rg) pk[rg] = f2bf(acc[nt][rg] + bias);
            *(ushort4t*)&Vt[((size_t)b * 64 + h) * TT + t] = pk;
        }
    }
}

// ---------------------------------------------------------------------------
// Flash attention partials. ROUND 10: 4-wave blocks (256 thr), each wave
// owns an independent chunk c = 4*(blockIdx>>9) + waveId of the same
// (b, q-tile) — no shared state, no barriers, zero LDS. Coarser block
// granularity fixes the 14%-occupancy churn of 1-wave blocks.
// Per wave: double-buffered K-frag prefetch, swapped QK^T, in-register P
// redistribution (dual ds_bpermute + dest-half select), setprio on MFMA.
// ---------------------------------------------------------------------------
#define LOADK(KF, T)                                                          \
    { const unsigned short* p_ = kp0 + (size_t)(T) * 4096;                    \
      KF[0][0] = *(const bfrag*)(p_);         KF[0][1] = *(const bfrag*)(p_ + 32);   \
      KF[1][0] = *(const bfrag*)(p_ + 1024);  KF[1][1] = *(const bfrag*)(p_ + 1056); \
      KF[2][0] = *(const bfrag*)(p_ + 2048);  KF[2][1] = *(const bfrag*)(p_ + 2080); \
      KF[3][0] = *(const bfrag*)(p_ + 3072);  KF[3][1] = *(const bfrag*)(p_ + 3104); }

#define LOADV(VF, T)                                                          \
    { const unsigned short* p_ = vp0 + (T) * 64;                              \
      VF[0][0] = *(const bfrag*)(p_);             VF[0][1] = *(const bfrag*)(p_ + 32);           \
      VF[1][0] = *(const bfrag*)(p_ + 16 * TT);   VF[1][1] = *(const bfrag*)(p_ + 16 * TT + 32); \
      VF[2][0] = *(const bfrag*)(p_ + 32 * TT);   VF[2][1] = *(const bfrag*)(p_ + 32 * TT + 32); \
      VF[3][0] = *(const bfrag*)(p_ + 48 * TT);   VF[3][1] = *(const bfrag*)(p_ + 48 * TT + 32); }

#define COMPUTE(KF, VF, T)                                                    \
{                                                                             \
    const int  kt_   = kt0 + (T);                                             \
    const bool diag_ = (kt_ == nkt - 1);                                      \
    const int  k0_   = kt_ * 64;                                              \
    _Pragma("unroll")                                                         \
    for (int s = 0; s < 2; ++s) {                                             \
        f32x4 sv[4];                                                          \
        __builtin_amdgcn_s_setprio(1);                                        \
        _Pragma("unroll")                                                     \
        for (int nt = 0; nt < 4; ++nt) {                                      \
            sv[nt] = (f32x4){0.f, 0.f, 0.f, 0.f};                             \
            sv[nt] = __builtin_amdgcn_mfma_f32_16x16x32_bf16(KF[nt][0], qa[s][0], sv[nt], 0, 0, 0); \
            sv[nt] = __builtin_amdgcn_mfma_f32_16x16x32_bf16(KF[nt][1], qa[s][1], sv[nt], 0, 0, 0); \
        }                                                                     \
        __builtin_amdgcn_s_setprio(0);                                        \
        const int qrow_ = q0 + s * 16 + lr;                                   \
        if (diag_) {                                                          \
            _Pragma("unroll")                                                 \
            for (int nt = 0; nt < 4; ++nt)                                    \
                _Pragma("unroll")                                             \
                for (int rg = 0; rg < 4; ++rg) {                              \
                    const int key_ = k0_ + nt * 16 + 4 * g + rg;              \
                    if (key_ > qrow_) sv[nt][rg] = -1e30f;                    \
                }                                                             \
        }                                                                     \
        float pm = fmaxf(fmaxf(fmaxf(sv[0][0], sv[0][1]), fmaxf(sv[0][2], sv[0][3])),   \
                         fmaxf(fmaxf(sv[1][0], sv[1][1]), fmaxf(sv[1][2], sv[1][3])));  \
        pm = fmaxf(pm, fmaxf(fmaxf(fmaxf(sv[2][0], sv[2][1]), fmaxf(sv[2][2], sv[2][3])),   \
                             fmaxf(fmaxf(sv[3][0], sv[3][1]), fmaxf(sv[3][2], sv[3][3])))); \
        pm = fmaxf(pm, __shfl_xor(pm, 16));                                   \
        pm = fmaxf(pm, __shfl_xor(pm, 32));                                   \
        if (!__all(pm - mrow[s] <= 8.0f)) {                                   \
            const float nm_ = fmaxf(mrow[s], pm);                             \
            const float cr_ = exp2f(mrow[s] - nm_);                           \
            mrow[s] = nm_;                                                    \
            lrow[s] *= cr_;                                                   \
            _Pragma("unroll")                                                 \
            for (int ht = 0; ht < 4; ++ht) o[s][ht] *= cr_;                   \
        }                                                                     \
        float ls = 0.f;                                                       \
        uint32 pw[8];                                                         \
        _Pragma("unroll")                                                     \
        for (int nt = 0; nt < 4; ++nt)                                        \
            _Pragma("unroll")                                                 \
            for (int h = 0; h < 2; ++h) {                                     \
                const float pa_ = exp2f(sv[nt][2 * h]     - mrow[s]);         \
                const float pb_ = exp2f(sv[nt][2 * h + 1] - mrow[s]);         \
                ls += pa_ + pb_;                                              \
                pw[nt * 2 + h] = pk2(pa_, pb_);                               \
            }                                                                 \
        ls += __shfl_xor(ls, 16);                                             \
        ls += __shfl_xor(ls, 32);                                             \
        lrow[s] += ls;                                                        \
        _Pragma("unroll")                                                     \
        for (int cc = 0; cc < 2; ++cc) {                                      \
            uint32x4 dw;                                                      \
            _Pragma("unroll")                                                 \
            for (int w2 = 0; w2 < 4; ++w2) {                                  \
                const int addr_ = (w2 < 2) ? addr_a : addr_b;                 \
                const uint32 lo_ = (uint32)__builtin_amdgcn_ds_bpermute(      \
                    addr_, (int)pw[4 * cc + (w2 & 1)]);                       \
                const uint32 hi_ = (uint32)__builtin_amdgcn_ds_bpermute(      \
                    addr_, (int)pw[4 * cc + 2 + (w2 & 1)]);                   \
                dw[w2] = ghi ? hi_ : lo_;                                     \
            }                                                                 \
            const bfrag paf_ = __builtin_bit_cast(bfrag, dw);                 \
            __builtin_amdgcn_s_setprio(1);                                    \
            o[s][0] = __builtin_amdgcn_mfma_f32_16x16x32_bf16(paf_, VF[0][cc], o[s][0], 0, 0, 0); \
            o[s][1] = __builtin_amdgcn_mfma_f32_16x16x32_bf16(paf_, VF[1][cc], o[s][1], 0, 0, 0); \
            o[s][2] = __builtin_amdgcn_mfma_f32_16x16x32_bf16(paf_, VF[2][cc], o[s][2], 0, 0, 0); \
            o[s][3] = __builtin_amdgcn_mfma_f32_16x16x32_bf16(paf_, VF[3][cc], o[s][3], 0, 0, 0); \
            __builtin_amdgcn_s_setprio(0);                                    \
        }                                                                     \
    }                                                                         \
}

template<int CHUNK>
__global__ __launch_bounds__(256, 2) void attn_part(
    const unsigned short* __restrict__ Qb,
    const unsigned short* __restrict__ Kb,
    const unsigned short* __restrict__ Vt,
    unsigned short* __restrict__ po, float* __restrict__ pml)
{
    constexpr int NCH = 64 / CHUNK;
    const int idx   = blockIdx.x;
    const int wid   = threadIdx.x >> 6;
    const int c     = (idx >> 9) * 4 + wid;       // wave-private chunk layer
    const int layer = idx & 511;
    const int b     = layer & 3;
    const int ti32  = 127 - ((layer >> 2) & 127); // heavy-first
    const int nkt   = (ti32 >> 1) + 1;
    const int kt0   = c * CHUNK;
    if (kt0 >= nkt) return;                        // no barriers in kernel
    const int ntile = min(nkt - kt0, CHUNK);

    const int l  = threadIdx.x & 63;
    const int lr = l & 15, g = l >> 4;
    const int q0 = ti32 * 32;
    const size_t bTT = (size_t)b * TT;

    // Q fragments (B-operand): lane holds Q[q0+s*16+lr][k=g*8..+7]
    bfrag qa[2][2];
#pragma unroll
    for (int s = 0; s < 2; ++s) {
        const size_t qr = (bTT + q0 + s * 16 + lr) * 64 + g * 8;
        qa[s][0] = *(const bfrag*)&Qb[qr];
        qa[s][1] = *(const bfrag*)&Qb[qr + 32];
    }

    // hoisted base pointers (elements)
    const unsigned short* kp0 = Kb + (bTT + (size_t)kt0 * 64 + lr) * 64 + g * 8;
    const unsigned short* vp0 = Vt + ((size_t)b * 64 + lr) * TT + (size_t)kt0 * 64 + g * 8;

    // bpermute lane addresses (bytes): w2<2 -> lane lr+32*(g&1); w2>=2 -> +16
    const int addr_a = (lr + 32 * (g & 1)) * 4;
    const int addr_b = addr_a + 64;
    const bool ghi = (g >= 2);

    f32x4 o[2][4];
#pragma unroll
    for (int s = 0; s < 2; ++s)
#pragma unroll
        for (int ht = 0; ht < 4; ++ht) o[s][ht] = (f32x4){0.f, 0.f, 0.f, 0.f};
    float mrow[2] = {-1e30f, -1e30f};
    float lrow[2] = {0.f, 0.f};

    // double-buffered K frags; V single-buffered (latency hides under softmax)
    bfrag kfA[4][2], kfB[4][2], vf[4][2];
    LOADK(kfA, 0);

#pragma unroll
    for (int t = 0; t < CHUNK; t += 2) {
        if (t >= ntile) break;
        LOADV(vf, t);
        if (t + 1 < ntile) LOADK(kfB, t + 1);
        COMPUTE(kfA, vf, t);
        if (t + 1 >= ntile) break;
        LOADV(vf, t + 1);
        if (t + 2 < ntile) LOADK(kfA, t + 2);
        COMPUTE(kfB, vf, t + 1);
    }

    // store partials: po coded C-layout bf16 (coalesced), pml (m,l) f32
    const int slot = (((b << 7) + ti32) * NCH) + c;
    const size_t pob = (size_t)slot * 2048;
#pragma unroll
    for (int s = 0; s < 2; ++s)
#pragma unroll
        for (int ht = 0; ht < 4; ++ht)
#pragma unroll
            for (int rg = 0; rg < 4; ++rg)
                po[pob + (size_t)(((s * 4 + ht) * 4 + rg) * 64 + l)] = f2bf(o[s][ht][rg]);
    if (g == 0) {
#pragma unroll
        for (int s = 0; s < 2; ++s) {
            pml[slot * 64 + s * 16 + lr]      = mrow[s];
            pml[slot * 64 + 32 + s * 16 + lr] = lrow[s];
        }
    }
}

// ---------------------------------------------------------------------------
// Merge split-K partials. grid = 512 (one per (b, ti32)), 256 threads; each
// thread owns 8 coded elements (same row, 8 consecutive cols).
// ---------------------------------------------------------------------------
__global__ __launch_bounds__(256) void attn_merge(
    const unsigned short* __restrict__ po, const float* __restrict__ pml,
    float* __restrict__ out, int chunk, int nch)
{
    const int idx  = blockIdx.x;      // 0..511
    const int b    = idx & 3;
    const int ti32 = idx >> 2;
    const int nkt  = (ti32 >> 1) + 1;
    const int nc   = (nkt + chunk - 1) / chunk;

    const int e0   = threadIdx.x * 8;
    const int lane = e0 & 63;
    const int rg   = (e0 >> 6) & 3;
    const int ht   = (e0 >> 8) & 3;
    const int s    = e0 >> 10;
    const int row  = s * 16 + ((lane >> 4) << 2) + rg;
    const int col0 = ht * 16 + (lane & 15);
    const int slot0 = ((b << 7) + ti32) * nch;

    float M = -1e30f;
    for (int c = 0; c < nc; ++c)
        M = fmaxf(M, pml[(slot0 + c) * 64 + row]);

    float den = 0.f;
    float acc[8];
#pragma unroll
    for (int i = 0; i < 8; ++i) acc[i] = 0.f;

    for (int c = 0; c < nc; ++c) {
        const float wgt = exp2f(pml[(slot0 + c) * 64 + row] - M);
        den += wgt * pml[(slot0 + c) * 64 + 32 + row];
        const ushort8t v = *(const ushort8t*)&po[(size_t)(slot0 + c) * 2048 + e0];
#pragma unroll
        for (int j = 0; j < 8; ++j) acc[j] += wgt * bf2f(v[j]);
    }
    const float inv = 1.0f / den;
    float* dst = out + ((size_t)b * TT + ti32 * 32 + row) * 64 + col0;
    float4 o0 = {acc[0] * inv, acc[1] * inv, acc[2] * inv, acc[3] * inv};
    float4 o1 = {acc[4] * inv, acc[5] * inv, acc[6] * inv, acc[7] * inv};
    *(float4*)(dst)     = o0;
    *(float4*)(dst + 4) = o1;
}

// ---------------------------------------------------------------------------
extern "C" void kernel_launch(void* const* d_in, const int* in_sizes, int n_in,
                              void* d_out, int out_size, void* d_ws, size_t ws_size,
                              hipStream_t stream)
{
    const float* emb = (const float*)d_in[0];
    const float* Wk  = (const float*)d_in[1];
    const float* bk  = (const float*)d_in[2];
    const float* Wq  = (const float*)d_in[3];
    const float* bq  = (const float*)d_in[4];
    const float* Wv  = (const float*)d_in[5];
    const float* bv  = (const float*)d_in[6];
    float* out = (float*)d_out;

    // ws: Qb[2MB] Kb[2MB] Vt[2MB] Wt[384KB] | po (bf16) | pml (f32)
    char* base = (char*)d_ws;
    unsigned short* Qb = (unsigned short*)(base);
    unsigned short* Kb = (unsigned short*)(base + (2u << 20));
    unsigned short* Vt = (unsigned short*)(base + (4u << 20));
    unsigned short* Wt = (unsigned short*)(base + (6u << 20));
    const size_t pbase = ((size_t)6 << 20) + (512u << 10);   // 6.5 MB

    // split-K ladder: nch=16 (42.2MB) if it fits, else nch=8 (24.3MB)
    int nch = 16;
    {
        const size_t need16 = pbase +
            (size_t)512 * 16 * (2048 * sizeof(unsigned short) + 64 * sizeof(float));
        if (need16 > ws_size) nch = 8;
    }
    const int chunk = 64 / nch;
    unsigned short* po = (unsigned short*)(base + pbase);
    float* pml = (float*)(po + (size_t)512 * nch * 2048);

    prep_wt<<<192 * 1024 / 256, 256, 0, stream>>>(Wk, Wq, Wv, Wt);
    qkv_mfma<<<(NB * TT) / 64, 256, 0, stream>>>(emb, Wt, bk, bq, bv, Qb, Kb, Vt);
    if (nch == 16)
        attn_part<4><<<512 * 4, 256, 0, stream>>>(Qb, Kb, Vt, po, pml);
    else
        attn_part<8><<<512 * 2, 256, 0, stream>>>(Qb, Kb, Vt, po, pml);
    attn_merge<<<512, 256, 0, stream>>>(po, pml, out, chunk, nch);
}

// Round 11
// 88.741 us; speedup vs baseline: 1.0062x; 1.0062x over previous
//
#include <hip/hip_runtime.h>
#include <hip/hip_bf16.h>

// SelfAttentionHead: EMB=1024, KEY=HEAD=64, B=4, T=4096
#define EMB 1024
#define NB  4
#define TT  4096
#define DD  64

// fold 1/sqrt(64) and log2(e) into Q so softmax runs in exp2 domain
static constexpr float SCALE2 = 0.125f * 1.4426950408889634f;

typedef __bf16          bfrag    __attribute__((ext_vector_type(8)));
typedef float           f32x4    __attribute__((ext_vector_type(4)));
typedef unsigned short  ushort8t __attribute__((ext_vector_type(8)));
typedef unsigned short  ushort4t __attribute__((ext_vector_type(4)));
typedef unsigned int    uint32;
typedef uint32          uint32x4 __attribute__((ext_vector_type(4)));

__device__ __forceinline__ unsigned short f2bf(float f) {
    __hip_bfloat16 h = __float2bfloat16(f);   // RNE
    return __builtin_bit_cast(unsigned short, h);
}
__device__ __forceinline__ float bf2f(unsigned short u) {
    uint32 v = ((uint32)u) << 16;
    return __builtin_bit_cast(float, v);
}
__device__ __forceinline__ uint32 pk2(float a, float b) {
    return (uint32)f2bf(a) | ((uint32)f2bf(b) << 16);
}

// ---------------------------------------------------------------------------
// Prep: Wt[n][k] bf16, n in [0,192) = concat(Wk, Wq*SCALE2, Wv) columns.
// ---------------------------------------------------------------------------
__global__ __launch_bounds__(256) void prep_wt(
    const float* __restrict__ Wk, const float* __restrict__ Wq,
    const float* __restrict__ Wv, unsigned short* __restrict__ Wt)
{
    const int o = blockIdx.x * 256 + threadIdx.x;   // 0 .. 192*1024-1
    const int n = o >> 10, k = o & 1023;
    float v;
    if (n < 64)       v = Wk[k * 64 + n];
    else if (n < 128) v = Wq[k * 64 + (n - 64)] * SCALE2;
    else              v = Wv[k * 64 + (n - 128)];
    Wt[o] = f2bf(v);
}

// ---------------------------------------------------------------------------
// QKV projection. ROUND 11: N-split — grid = 512 blocks: (m-tile = bid>>1,
// N-half = bid&1). Each block computes M64 x N96 (acc 6), staging only its
// 96 W rows (total W LDS traffic unchanged vs M64xN192; emb HBM-read once
// via L2). 2 blocks/CU co-resident -> barrier drains overlap. Inner
// structure (T14 reg-prefetch) is the round-4/8 proven one.
// ---------------------------------------------------------------------------
#define PSTR 66

__global__ __launch_bounds__(256) void qkv_mfma(
    const float* __restrict__ emb,
    const unsigned short* __restrict__ Wt,
    const float* __restrict__ bk, const float* __restrict__ bq,
    const float* __restrict__ bv,
    unsigned short* __restrict__ Qb, unsigned short* __restrict__ Kb,
    unsigned short* __restrict__ Vt)
{
    __shared__ unsigned short elds[64 * PSTR];
    __shared__ unsigned short wlds[96 * PSTR];

    const int tid = threadIdx.x;
    const int w = tid >> 6, l = tid & 63;
    const int lr = l & 15, lg = l >> 4;
    const int m0    = (blockIdx.x >> 1) * 64;
    const int nbase = (blockIdx.x & 1) * 96;

    f32x4 acc[6];
#pragma unroll
    for (int i = 0; i < 6; ++i) acc[i] = (f32x4){0.f, 0.f, 0.f, 0.f};

    const int er = tid >> 2, ec = (tid & 3) * 16;

    float4 f0, f1, f2, f3;
    ushort8t wr[3];
    {   // prologue: load k0 = 0 tiles into regs
        const float* src = emb + (size_t)(m0 + er) * EMB + ec;
        f0 = *(const float4*)(src + 0);
        f1 = *(const float4*)(src + 4);
        f2 = *(const float4*)(src + 8);
        f3 = *(const float4*)(src + 12);
#pragma unroll
        for (int i = 0; i < 3; ++i) {
            const int idx = tid + i * 256;
            const int row = idx >> 3, c = (idx & 7) * 8;
            wr[i] = *(const ushort8t*)&Wt[(size_t)(nbase + row) * 1024 + c];
        }
    }

    for (int it = 0; it < 16; ++it) {
        __syncthreads();   // previous iteration's MFMA reads are done
        {   // write staged regs -> LDS (f32 -> bf16 for emb)
            ushort8t lo, hi;
            lo[0]=f2bf(f0.x); lo[1]=f2bf(f0.y); lo[2]=f2bf(f0.z); lo[3]=f2bf(f0.w);
            lo[4]=f2bf(f1.x); lo[5]=f2bf(f1.y); lo[6]=f2bf(f1.z); lo[7]=f2bf(f1.w);
            hi[0]=f2bf(f2.x); hi[1]=f2bf(f2.y); hi[2]=f2bf(f2.z); hi[3]=f2bf(f2.w);
            hi[4]=f2bf(f3.x); hi[5]=f2bf(f3.y); hi[6]=f2bf(f3.z); hi[7]=f2bf(f3.w);
            *(ushort8t*)&elds[er * PSTR + ec]     = lo;
            *(ushort8t*)&elds[er * PSTR + ec + 8] = hi;
#pragma unroll
            for (int i = 0; i < 3; ++i) {
                const int idx = tid + i * 256;
                const int row = idx >> 3, c = (idx & 7) * 8;
                *(ushort8t*)&wlds[row * PSTR + c] = wr[i];
            }
        }
        // prefetch next k-step into regs (completes under the MFMA phase)
        if (it < 15) {
            const int kn = (it + 1) * 64;
            const float* src = emb + (size_t)(m0 + er) * EMB + kn + ec;
            f0 = *(const float4*)(src + 0);
            f1 = *(const float4*)(src + 4);
            f2 = *(const float4*)(src + 8);
            f3 = *(const float4*)(src + 12);
#pragma unroll
            for (int i = 0; i < 3; ++i) {
                const int idx = tid + i * 256;
                const int row = idx >> 3, c = (idx & 7) * 8;
                wr[i] = *(const ushort8t*)&Wt[(size_t)(nbase + row) * 1024 + kn + c];
            }
        }
        __syncthreads();
#pragma unroll
        for (int c = 0; c < 2; ++c) {
            bfrag a = *(const bfrag*)&elds[(w * 16 + lr) * PSTR + c * 32 + lg * 8];
#pragma unroll
            for (int nt = 0; nt < 6; ++nt) {
                bfrag bb = *(const bfrag*)&wlds[(nt * 16 + lr) * PSTR + c * 32 + lg * 8];
                acc[nt] = __builtin_amdgcn_mfma_f32_16x16x32_bf16(a, bb, acc[nt], 0, 0, 0);
            }
        }
    }

    // epilogue: C layout col=lane&15, row=(lane>>4)*4+reg; n decides K/Q/V
    const int rbase = m0 + w * 16 + lg * 4;
#pragma unroll
    for (int nt = 0; nt < 6; ++nt) {
        const int n = nbase + nt * 16 + lr;
        float bias;
        if (n < 64)       bias = bk[n];
        else if (n < 128) bias = bq[n - 64] * SCALE2;
        else              bias = bv[n - 128];
        if (n < 128) {
            unsigned short* dst = (n < 64) ? Kb : Qb;
            const int d = (n < 64) ? n : (n - 64);
#pragma unroll
            for (int rg = 0; rg < 4; ++rg)
                dst[(size_t)(rbase + rg) * 64 + d] = f2bf(acc[nt][rg] + bias);
        } else {
            const int h = n - 128;
            const int b = rbase >> 12, t = rbase & (TT - 1);
            ushort4t pk;
#pragma unroll
            for (int rg = 0; rg < 4; ++rg) pk[rg] = f2bf(acc[nt][rg] + bias);
            *(ushort4t*)&Vt[((size_t)b * 64 + h) * TT + t] = pk;
        }
    }
}

// ---------------------------------------------------------------------------
// Flash attention partials (round-9 measured-best, reverted from r10):
// 1-wave blocks, zero LDS, no barriers, split-K with compile-time CHUNK.
// Double-buffered K-frag prefetch; swapped QK^T; in-register P
// redistribution via dual ds_bpermute + dest-half select; setprio on MFMA.
// ---------------------------------------------------------------------------
#define LOADK(KF, T)                                                          \
    { const unsigned short* p_ = kp0 + (size_t)(T) * 4096;                    \
      KF[0][0] = *(const bfrag*)(p_);         KF[0][1] = *(const bfrag*)(p_ + 32);   \
      KF[1][0] = *(const bfrag*)(p_ + 1024);  KF[1][1] = *(const bfrag*)(p_ + 1056); \
      KF[2][0] = *(const bfrag*)(p_ + 2048);  KF[2][1] = *(const bfrag*)(p_ + 2080); \
      KF[3][0] = *(const bfrag*)(p_ + 3072);  KF[3][1] = *(const bfrag*)(p_ + 3104); }

#define LOADV(VF, T)                                                          \
    { const unsigned short* p_ = vp0 + (T) * 64;                              \
      VF[0][0] = *(const bfrag*)(p_);             VF[0][1] = *(const bfrag*)(p_ + 32);           \
      VF[1][0] = *(const bfrag*)(p_ + 16 * TT);   VF[1][1] = *(const bfrag*)(p_ + 16 * TT + 32); \
      VF[2][0] = *(const bfrag*)(p_ + 32 * TT);   VF[2][1] = *(const bfrag*)(p_ + 32 * TT + 32); \
      VF[3][0] = *(const bfrag*)(p_ + 48 * TT);   VF[3][1] = *(const bfrag*)(p_ + 48 * TT + 32); }

#define COMPUTE(KF, VF, T)                                                    \
{                                                                             \
    const int  kt_   = kt0 + (T);                                             \
    const bool diag_ = (kt_ == nkt - 1);                                      \
    const int  k0_   = kt_ * 64;                                              \
    _Pragma("unroll")                                                         \
    for (int s = 0; s < 2; ++s) {                                             \
        f32x4 sv[4];                                                          \
        __builtin_amdgcn_s_setprio(1);                                        \
        _Pragma("unroll")                                                     \
        for (int nt = 0; nt < 4; ++nt) {                                      \
            sv[nt] = (f32x4){0.f, 0.f, 0.f, 0.f};                             \
            sv[nt] = __builtin_amdgcn_mfma_f32_16x16x32_bf16(KF[nt][0], qa[s][0], sv[nt], 0, 0, 0); \
            sv[nt] = __builtin_amdgcn_mfma_f32_16x16x32_bf16(KF[nt][1], qa[s][1], sv[nt], 0, 0, 0); \
        }                                                                     \
        __builtin_amdgcn_s_setprio(0);                                        \
        const int qrow_ = q0 + s * 16 + lr;                                   \
        if (diag_) {                                                          \
            _Pragma("unroll")                                                 \
            for (int nt = 0; nt < 4; ++nt)                                    \
                _Pragma("unroll")                                             \
                for (int rg = 0; rg < 4; ++rg) {                              \
                    const int key_ = k0_ + nt * 16 + 4 * g + rg;              \
                    if (key_ > qrow_) sv[nt][rg] = -1e30f;                    \
                }                                                             \
        }                                                                     \
        float pm = fmaxf(fmaxf(fmaxf(sv[0][0], sv[0][1]), fmaxf(sv[0][2], sv[0][3])),   \
                         fmaxf(fmaxf(sv[1][0], sv[1][1]), fmaxf(sv[1][2], sv[1][3])));  \
        pm = fmaxf(pm, fmaxf(fmaxf(fmaxf(sv[2][0], sv[2][1]), fmaxf(sv[2][2], sv[2][3])),   \
                             fmaxf(fmaxf(sv[3][0], sv[3][1]), fmaxf(sv[3][2], sv[3][3])))); \
        pm = fmaxf(pm, __shfl_xor(pm, 16));                                   \
        pm = fmaxf(pm, __shfl_xor(pm, 32));                                   \
        if (!__all(pm - mrow[s] <= 8.0f)) {                                   \
            const float nm_ = fmaxf(mrow[s], pm);                             \
            const float cr_ = exp2f(mrow[s] - nm_);                           \
            mrow[s] = nm_;                                                    \
            lrow[s] *= cr_;                                                   \
            _Pragma("unroll")                                                 \
            for (int ht = 0; ht < 4; ++ht) o[s][ht] *= cr_;                   \
        }                                                                     \
        float ls = 0.f;                                                       \
        uint32 pw[8];                                                         \
        _Pragma("unroll")                                                     \
        for (int nt = 0; nt < 4; ++nt)                                        \
            _Pragma("unroll")                                                 \
            for (int h = 0; h < 2; ++h) {                                     \
                const float pa_ = exp2f(sv[nt][2 * h]     - mrow[s]);         \
                const float pb_ = exp2f(sv[nt][2 * h + 1] - mrow[s]);         \
                ls += pa_ + pb_;                                              \
                pw[nt * 2 + h] = pk2(pa_, pb_);                               \
            }                                                                 \
        ls += __shfl_xor(ls, 16);                                             \
        ls += __shfl_xor(ls, 32);                                             \
        lrow[s] += ls;                                                        \
        _Pragma("unroll")                                                     \
        for (int cc = 0; cc < 2; ++cc) {                                      \
            uint32x4 dw;                                                      \
            _Pragma("unroll")                                                 \
            for (int w2 = 0; w2 < 4; ++w2) {                                  \
                const int addr_ = (w2 < 2) ? addr_a : addr_b;                 \
                const uint32 lo_ = (uint32)__builtin_amdgcn_ds_bpermute(      \
                    addr_, (int)pw[4 * cc + (w2 & 1)]);                       \
                const uint32 hi_ = (uint32)__builtin_amdgcn_ds_bpermute(      \
                    addr_, (int)pw[4 * cc + 2 + (w2 & 1)]);                   \
                dw[w2] = ghi ? hi_ : lo_;                                     \
            }                                                                 \
            const bfrag paf_ = __builtin_bit_cast(bfrag, dw);                 \
            __builtin_amdgcn_s_setprio(1);                                    \
            o[s][0] = __builtin_amdgcn_mfma_f32_16x16x32_bf16(paf_, VF[0][cc], o[s][0], 0, 0, 0); \
            o[s][1] = __builtin_amdgcn_mfma_f32_16x16x32_bf16(paf_, VF[1][cc], o[s][1], 0, 0, 0); \
            o[s][2] = __builtin_amdgcn_mfma_f32_16x16x32_bf16(paf_, VF[2][cc], o[s][2], 0, 0, 0); \
            o[s][3] = __builtin_amdgcn_mfma_f32_16x16x32_bf16(paf_, VF[3][cc], o[s][3], 0, 0, 0); \
            __builtin_amdgcn_s_setprio(0);                                    \
        }                                                                     \
    }                                                                         \
}

template<int CHUNK>
__global__ __launch_bounds__(64, 2) void attn_part(
    const unsigned short* __restrict__ Qb,
    const unsigned short* __restrict__ Kb,
    const unsigned short* __restrict__ Vt,
    unsigned short* __restrict__ po, float* __restrict__ pml)
{
    constexpr int NCH = 64 / CHUNK;
    const int idx  = blockIdx.x;
    const int c    = idx >> 9;                    // chunk layer
    const int b    = idx & 3;
    const int ti32 = 127 - ((idx >> 2) & 127);    // heavy-first
    const int nkt  = (ti32 >> 1) + 1;
    const int kt0  = c * CHUNK;
    if (kt0 >= nkt) return;
    const int ntile = min(nkt - kt0, CHUNK);

    const int l  = threadIdx.x;
    const int lr = l & 15, g = l >> 4;
    const int q0 = ti32 * 32;
    const size_t bTT = (size_t)b * TT;

    // Q fragments (B-operand): lane holds Q[q0+s*16+lr][k=g*8..+7]
    bfrag qa[2][2];
#pragma unroll
    for (int s = 0; s < 2; ++s) {
        const size_t qr = (bTT + q0 + s * 16 + lr) * 64 + g * 8;
        qa[s][0] = *(const bfrag*)&Qb[qr];
        qa[s][1] = *(const bfrag*)&Qb[qr + 32];
    }

    // hoisted base pointers (elements)
    const unsigned short* kp0 = Kb + (bTT + (size_t)kt0 * 64 + lr) * 64 + g * 8;
    const unsigned short* vp0 = Vt + ((size_t)b * 64 + lr) * TT + (size_t)kt0 * 64 + g * 8;

    // bpermute lane addresses (bytes): w2<2 -> lane lr+32*(g&1); w2>=2 -> +16
    const int addr_a = (lr + 32 * (g & 1)) * 4;
    const int addr_b = addr_a + 64;
    const bool ghi = (g >= 2);

    f32x4 o[2][4];
#pragma unroll
    for (int s = 0; s < 2; ++s)
#pragma unroll
        for (int ht = 0; ht < 4; ++ht) o[s][ht] = (f32x4){0.f, 0.f, 0.f, 0.f};
    float mrow[2] = {-1e30f, -1e30f};
    float lrow[2] = {0.f, 0.f};

    // double-buffered K frags; V single-buffered (latency hides under softmax)
    bfrag kfA[4][2], kfB[4][2], vf[4][2];
    LOADK(kfA, 0);

#pragma unroll
    for (int t = 0; t < CHUNK; t += 2) {
        if (t >= ntile) break;
        LOADV(vf, t);
        if (t + 1 < ntile) LOADK(kfB, t + 1);
        COMPUTE(kfA, vf, t);
        if (t + 1 >= ntile) break;
        LOADV(vf, t + 1);
        if (t + 2 < ntile) LOADK(kfA, t + 2);
        COMPUTE(kfB, vf, t + 1);
    }

    // store partials: po coded C-layout bf16 (coalesced), pml (m,l) f32
    const int slot = (((b << 7) + ti32) * NCH) + c;
    const size_t pob = (size_t)slot * 2048;
#pragma unroll
    for (int s = 0; s < 2; ++s)
#pragma unroll
        for (int ht = 0; ht < 4; ++ht)
#pragma unroll
            for (int rg = 0; rg < 4; ++rg)
                po[pob + (size_t)(((s * 4 + ht) * 4 + rg) * 64 + l)] = f2bf(o[s][ht][rg]);
    if (g == 0) {
#pragma unroll
        for (int s = 0; s < 2; ++s) {
            pml[slot * 64 + s * 16 + lr]      = mrow[s];
            pml[slot * 64 + 32 + s * 16 + lr] = lrow[s];
        }
    }
}

// ---------------------------------------------------------------------------
// Merge split-K partials. grid = 512 (one per (b, ti32)), 256 threads; each
// thread owns 8 coded elements (same row, 8 consecutive cols).
// ---------------------------------------------------------------------------
__global__ __launch_bounds__(256) void attn_merge(
    const unsigned short* __restrict__ po, const float* __restrict__ pml,
    float* __restrict__ out, int chunk, int nch)
{
    const int idx  = blockIdx.x;      // 0..511
    const int b    = idx & 3;
    const int ti32 = idx >> 2;
    const int nkt  = (ti32 >> 1) + 1;
    const int nc   = (nkt + chunk - 1) / chunk;

    const int e0   = threadIdx.x * 8;
    const int lane = e0 & 63;
    const int rg   = (e0 >> 6) & 3;
    const int ht   = (e0 >> 8) & 3;
    const int s    = e0 >> 10;
    const int row  = s * 16 + ((lane >> 4) << 2) + rg;
    const int col0 = ht * 16 + (lane & 15);
    const int slot0 = ((b << 7) + ti32) * nch;

    float M = -1e30f;
    for (int c = 0; c < nc; ++c)
        M = fmaxf(M, pml[(slot0 + c) * 64 + row]);

    float den = 0.f;
    float acc[8];
#pragma unroll
    for (int i = 0; i < 8; ++i) acc[i] = 0.f;

    for (int c = 0; c < nc; ++c) {
        const float wgt = exp2f(pml[(slot0 + c) * 64 + row] - M);
        den += wgt * pml[(slot0 + c) * 64 + 32 + row];
        const ushort8t v = *(const ushort8t*)&po[(size_t)(slot0 + c) * 2048 + e0];
#pragma unroll
        for (int j = 0; j < 8; ++j) acc[j] += wgt * bf2f(v[j]);
    }
    const float inv = 1.0f / den;
    float* dst = out + ((size_t)b * TT + ti32 * 32 + row) * 64 + col0;
    float4 o0 = {acc[0] * inv, acc[1] * inv, acc[2] * inv, acc[3] * inv};
    float4 o1 = {acc[4] * inv, acc[5] * inv, acc[6] * inv, acc[7] * inv};
    *(float4*)(dst)     = o0;
    *(float4*)(dst + 4) = o1;
}

// ---------------------------------------------------------------------------
extern "C" void kernel_launch(void* const* d_in, const int* in_sizes, int n_in,
                              void* d_out, int out_size, void* d_ws, size_t ws_size,
                              hipStream_t stream)
{
    const float* emb = (const float*)d_in[0];
    const float* Wk  = (const float*)d_in[1];
    const float* bk  = (const float*)d_in[2];
    const float* Wq  = (const float*)d_in[3];
    const float* bq  = (const float*)d_in[4];
    const float* Wv  = (const float*)d_in[5];
    const float* bv  = (const float*)d_in[6];
    float* out = (float*)d_out;

    // ws: Qb[2MB] Kb[2MB] Vt[2MB] Wt[384KB] | po (bf16) | pml (f32)
    char* base = (char*)d_ws;
    unsigned short* Qb = (unsigned short*)(base);
    unsigned short* Kb = (unsigned short*)(base + (2u << 20));
    unsigned short* Vt = (unsigned short*)(base + (4u << 20));
    unsigned short* Wt = (unsigned short*)(base + (6u << 20));
    const size_t pbase = ((size_t)6 << 20) + (512u << 10);   // 6.5 MB

    // split-K ladder: nch=16 (42.2MB) if it fits, else nch=8 (24.3MB)
    int nch = 16;
    {
        const size_t need16 = pbase +
            (size_t)512 * 16 * (2048 * sizeof(unsigned short) + 64 * sizeof(float));
        if (need16 > ws_size) nch = 8;
    }
    const int chunk = 64 / nch;
    unsigned short* po = (unsigned short*)(base + pbase);
    float* pml = (float*)(po + (size_t)512 * nch * 2048);

    prep_wt<<<192 * 1024 / 256, 256, 0, stream>>>(Wk, Wq, Wv, Wt);
    qkv_mfma<<<(NB * TT / 64) * 2, 256, 0, stream>>>(emb, Wt, bk, bq, bv, Qb, Kb, Vt);
    if (nch == 16)
        attn_part<4><<<512 * 16, 64, 0, stream>>>(Qb, Kb, Vt, po, pml);
    else
        attn_part<8><<<512 * 8, 64, 0, stream>>>(Qb, Kb, Vt, po, pml);
    attn_merge<<<512, 256, 0, stream>>>(po, pml, out, chunk, nch);
}

// Round 12
// 86.005 us; speedup vs baseline: 1.0382x; 1.0318x over previous
//
#include <hip/hip_runtime.h>
#include <hip/hip_bf16.h>

// SelfAttentionHead: EMB=1024, KEY=HEAD=64, B=4, T=4096
#define EMB 1024
#define NB  4
#define TT  4096
#define DD  64

// fold 1/sqrt(64) and log2(e) into Q so softmax runs in exp2 domain
static constexpr float SCALE2 = 0.125f * 1.4426950408889634f;

typedef __bf16          bfrag    __attribute__((ext_vector_type(8)));
typedef float           f32x4    __attribute__((ext_vector_type(4)));
typedef unsigned short  ushort8t __attribute__((ext_vector_type(8)));
typedef unsigned short  ushort4t __attribute__((ext_vector_type(4)));
typedef unsigned int    uint32;
typedef uint32          uint32x4 __attribute__((ext_vector_type(4)));

__device__ __forceinline__ unsigned short f2bf(float f) {
    __hip_bfloat16 h = __float2bfloat16(f);   // RNE
    return __builtin_bit_cast(unsigned short, h);
}
__device__ __forceinline__ float bf2f(unsigned short u) {
    uint32 v = ((uint32)u) << 16;
    return __builtin_bit_cast(float, v);
}
// T12 recipe: single-instruction packed f32->bf16 pair (a -> low 16, b -> high)
__device__ __forceinline__ uint32 pk2(float a, float b) {
    uint32 r;
    asm("v_cvt_pk_bf16_f32 %0, %1, %2" : "=v"(r) : "v"(a), "v"(b));
    return r;
}

// ---------------------------------------------------------------------------
// Prep: Wt[n][k] bf16, n in [0,192) = concat(Wk, Wq*SCALE2, Wv) columns.
// ---------------------------------------------------------------------------
__global__ __launch_bounds__(256) void prep_wt(
    const float* __restrict__ Wk, const float* __restrict__ Wq,
    const float* __restrict__ Wv, unsigned short* __restrict__ Wt)
{
    const int o = blockIdx.x * 256 + threadIdx.x;   // 0 .. 192*1024-1
    const int n = o >> 10, k = o & 1023;
    float v;
    if (n < 64)       v = Wk[k * 64 + n];
    else if (n < 128) v = Wq[k * 64 + (n - 64)] * SCALE2;
    else              v = Wv[k * 64 + (n - 128)];
    Wt[o] = f2bf(v);
}

// ---------------------------------------------------------------------------
// QKV projection (round-4/8 proven M64, reverted from r11's neutral N-split):
// bf16 MFMA GEMM, M-tile 64, 256 thr (4 waves), T14 reg-prefetch of next
// k-step's emb/W tiles. Outputs Q/K bf16 row-major (Q pre-scaled),
// V^T [b][h][t].
// ---------------------------------------------------------------------------
#define PSTR 66

__global__ __launch_bounds__(256) void qkv_mfma(
    const float* __restrict__ emb,
    const unsigned short* __restrict__ Wt,
    const float* __restrict__ bk, const float* __restrict__ bq,
    const float* __restrict__ bv,
    unsigned short* __restrict__ Qb, unsigned short* __restrict__ Kb,
    unsigned short* __restrict__ Vt)
{
    __shared__ unsigned short elds[64 * PSTR];
    __shared__ unsigned short wlds[192 * PSTR];

    const int tid = threadIdx.x;
    const int w = tid >> 6, l = tid & 63;
    const int lr = l & 15, lg = l >> 4;
    const int m0 = blockIdx.x * 64;

    f32x4 acc[12];
#pragma unroll
    for (int i = 0; i < 12; ++i) acc[i] = (f32x4){0.f, 0.f, 0.f, 0.f};

    const int er = tid >> 2, ec = (tid & 3) * 16;

    float4 f0, f1, f2, f3;
    ushort8t wr[6];
    {   // prologue: load k0 = 0 tiles into regs
        const float* src = emb + (size_t)(m0 + er) * EMB + ec;
        f0 = *(const float4*)(src + 0);
        f1 = *(const float4*)(src + 4);
        f2 = *(const float4*)(src + 8);
        f3 = *(const float4*)(src + 12);
#pragma unroll
        for (int i = 0; i < 6; ++i) {
            const int idx = tid + i * 256;
            const int row = idx >> 3, c = (idx & 7) * 8;
            wr[i] = *(const ushort8t*)&Wt[(size_t)row * 1024 + c];
        }
    }

    for (int it = 0; it < 16; ++it) {
        __syncthreads();   // previous iteration's MFMA reads are done
        {   // write staged regs -> LDS (f32 -> bf16 for emb)
            ushort8t lo, hi;
            lo[0]=f2bf(f0.x); lo[1]=f2bf(f0.y); lo[2]=f2bf(f0.z); lo[3]=f2bf(f0.w);
            lo[4]=f2bf(f1.x); lo[5]=f2bf(f1.y); lo[6]=f2bf(f1.z); lo[7]=f2bf(f1.w);
            hi[0]=f2bf(f2.x); hi[1]=f2bf(f2.y); hi[2]=f2bf(f2.z); hi[3]=f2bf(f2.w);
            hi[4]=f2bf(f3.x); hi[5]=f2bf(f3.y); hi[6]=f2bf(f3.z); hi[7]=f2bf(f3.w);
            *(ushort8t*)&elds[er * PSTR + ec]     = lo;
            *(ushort8t*)&elds[er * PSTR + ec + 8] = hi;
#pragma unroll
            for (int i = 0; i < 6; ++i) {
                const int idx = tid + i * 256;
                const int row = idx >> 3, c = (idx & 7) * 8;
                *(ushort8t*)&wlds[row * PSTR + c] = wr[i];
            }
        }
        // prefetch next k-step into regs (completes under the MFMA phase)
        if (it < 15) {
            const int kn = (it + 1) * 64;
            const float* src = emb + (size_t)(m0 + er) * EMB + kn + ec;
            f0 = *(const float4*)(src + 0);
            f1 = *(const float4*)(src + 4);
            f2 = *(const float4*)(src + 8);
            f3 = *(const float4*)(src + 12);
#pragma unroll
            for (int i = 0; i < 6; ++i) {
                const int idx = tid + i * 256;
                const int row = idx >> 3, c = (idx & 7) * 8;
                wr[i] = *(const ushort8t*)&Wt[(size_t)row * 1024 + kn + c];
            }
        }
        __syncthreads();
#pragma unroll
        for (int c = 0; c < 2; ++c) {
            bfrag a = *(const bfrag*)&elds[(w * 16 + lr) * PSTR + c * 32 + lg * 8];
#pragma unroll
            for (int nt = 0; nt < 12; ++nt) {
                bfrag bb = *(const bfrag*)&wlds[(nt * 16 + lr) * PSTR + c * 32 + lg * 8];
                acc[nt] = __builtin_amdgcn_mfma_f32_16x16x32_bf16(a, bb, acc[nt], 0, 0, 0);
            }
        }
    }

    const int rbase = m0 + w * 16 + lg * 4;
#pragma unroll
    for (int nt = 0; nt < 12; ++nt) {
        const int n = nt * 16 + lr;
        float bias;
        if (n < 64)       bias = bk[n];
        else if (n < 128) bias = bq[n - 64] * SCALE2;
        else              bias = bv[n - 128];
        if (nt < 8) {
            unsigned short* dst = (nt < 4) ? Kb : Qb;
            const int d = (nt < 4) ? n : (n - 64);
#pragma unroll
            for (int rg = 0; rg < 4; ++rg)
                dst[(size_t)(rbase + rg) * 64 + d] = f2bf(acc[nt][rg] + bias);
        } else {
            const int h = n - 128;
            const int b = rbase >> 12, t = rbase & (TT - 1);
            ushort4t pk;
#pragma unroll
            for (int rg = 0; rg < 4; ++rg) pk[rg] = f2bf(acc[nt][rg] + bias);
            *(ushort4t*)&Vt[((size_t)b * 64 + h) * TT + t] = pk;
        }
    }
}

// ---------------------------------------------------------------------------
// Flash attention partials (r9/r11 structure): 1-wave blocks, zero LDS, no
// barriers, split-K with compile-time CHUNK. ROUND 12: pk2 is now a single
// v_cvt_pk_bf16_f32; max reduction restructured into max3-fusable triples.
// ---------------------------------------------------------------------------
#define LOADK(KF, T)                                                          \
    { const unsigned short* p_ = kp0 + (size_t)(T) * 4096;                    \
      KF[0][0] = *(const bfrag*)(p_);         KF[0][1] = *(const bfrag*)(p_ + 32);   \
      KF[1][0] = *(const bfrag*)(p_ + 1024);  KF[1][1] = *(const bfrag*)(p_ + 1056); \
      KF[2][0] = *(const bfrag*)(p_ + 2048);  KF[2][1] = *(const bfrag*)(p_ + 2080); \
      KF[3][0] = *(const bfrag*)(p_ + 3072);  KF[3][1] = *(const bfrag*)(p_ + 3104); }

#define LOADV(VF, T)                                                          \
    { const unsigned short* p_ = vp0 + (T) * 64;                              \
      VF[0][0] = *(const bfrag*)(p_);             VF[0][1] = *(const bfrag*)(p_ + 32);           \
      VF[1][0] = *(const bfrag*)(p_ + 16 * TT);   VF[1][1] = *(const bfrag*)(p_ + 16 * TT + 32); \
      VF[2][0] = *(const bfrag*)(p_ + 32 * TT);   VF[2][1] = *(const bfrag*)(p_ + 32 * TT + 32); \
      VF[3][0] = *(const bfrag*)(p_ + 48 * TT);   VF[3][1] = *(const bfrag*)(p_ + 48 * TT + 32); }

#define COMPUTE(KF, VF, T)                                                    \
{                                                                             \
    const int  kt_   = kt0 + (T);                                             \
    const bool diag_ = (kt_ == nkt - 1);                                      \
    const int  k0_   = kt_ * 64;                                              \
    _Pragma("unroll")                                                         \
    for (int s = 0; s < 2; ++s) {                                             \
        f32x4 sv[4];                                                          \
        __builtin_amdgcn_s_setprio(1);                                        \
        _Pragma("unroll")                                                     \
        for (int nt = 0; nt < 4; ++nt) {                                      \
            sv[nt] = (f32x4){0.f, 0.f, 0.f, 0.f};                             \
            sv[nt] = __builtin_amdgcn_mfma_f32_16x16x32_bf16(KF[nt][0], qa[s][0], sv[nt], 0, 0, 0); \
            sv[nt] = __builtin_amdgcn_mfma_f32_16x16x32_bf16(KF[nt][1], qa[s][1], sv[nt], 0, 0, 0); \
        }                                                                     \
        __builtin_amdgcn_s_setprio(0);                                        \
        const int qrow_ = q0 + s * 16 + lr;                                   \
        if (diag_) {                                                          \
            _Pragma("unroll")                                                 \
            for (int nt = 0; nt < 4; ++nt)                                    \
                _Pragma("unroll")                                             \
                for (int rg = 0; rg < 4; ++rg) {                              \
                    const int key_ = k0_ + nt * 16 + 4 * g + rg;              \
                    if (key_ > qrow_) sv[nt][rg] = -1e30f;                    \
                }                                                             \
        }                                                                     \
        /* max over 16 regs as two max3 chains, then lanes lr+16k */          \
        float a0_ = fmaxf(fmaxf(sv[0][0], sv[0][1]), sv[0][2]);               \
        a0_ = fmaxf(fmaxf(a0_, sv[0][3]), sv[1][0]);                          \
        a0_ = fmaxf(fmaxf(a0_, sv[1][1]), sv[1][2]);                          \
        float a1_ = fmaxf(fmaxf(sv[2][0], sv[2][1]), sv[2][2]);               \
        a1_ = fmaxf(fmaxf(a1_, sv[2][3]), sv[3][0]);                          \
        a1_ = fmaxf(fmaxf(a1_, sv[3][1]), sv[3][2]);                          \
        float pm = fmaxf(fmaxf(a0_, sv[1][3]), fmaxf(a1_, sv[3][3]));         \
        pm = fmaxf(pm, __shfl_xor(pm, 16));                                   \
        pm = fmaxf(pm, __shfl_xor(pm, 32));                                   \
        if (!__all(pm - mrow[s] <= 8.0f)) {                                   \
            const float nm_ = fmaxf(mrow[s], pm);                             \
            const float cr_ = exp2f(mrow[s] - nm_);                           \
            mrow[s] = nm_;                                                    \
            lrow[s] *= cr_;                                                   \
            _Pragma("unroll")                                                 \
            for (int ht = 0; ht < 4; ++ht) o[s][ht] *= cr_;                   \
        }                                                                     \
        float ls = 0.f;                                                       \
        uint32 pw[8];                                                         \
        _Pragma("unroll")                                                     \
        for (int nt = 0; nt < 4; ++nt)                                        \
            _Pragma("unroll")                                                 \
            for (int h = 0; h < 2; ++h) {                                     \
                const float pa_ = exp2f(sv[nt][2 * h]     - mrow[s]);         \
                const float pb_ = exp2f(sv[nt][2 * h + 1] - mrow[s]);         \
                ls += pa_ + pb_;                                              \
                pw[nt * 2 + h] = pk2(pa_, pb_);                               \
            }                                                                 \
        ls += __shfl_xor(ls, 16);                                             \
        ls += __shfl_xor(ls, 32);                                             \
        lrow[s] += ls;                                                        \
        _Pragma("unroll")                                                     \
        for (int cc = 0; cc < 2; ++cc) {                                      \
            uint32x4 dw;                                                      \
            _Pragma("unroll")                                                 \
            for (int w2 = 0; w2 < 4; ++w2) {                                  \
                const int addr_ = (w2 < 2) ? addr_a : addr_b;                 \
                const uint32 lo_ = (uint32)__builtin_amdgcn_ds_bpermute(      \
                    addr_, (int)pw[4 * cc + (w2 & 1)]);                       \
                const uint32 hi_ = (uint32)__builtin_amdgcn_ds_bpermute(      \
                    addr_, (int)pw[4 * cc + 2 + (w2 & 1)]);                   \
                dw[w2] = ghi ? hi_ : lo_;                                     \
            }                                                                 \
            const bfrag paf_ = __builtin_bit_cast(bfrag, dw);                 \
            __builtin_amdgcn_s_setprio(1);                                    \
            o[s][0] = __builtin_amdgcn_mfma_f32_16x16x32_bf16(paf_, VF[0][cc], o[s][0], 0, 0, 0); \
            o[s][1] = __builtin_amdgcn_mfma_f32_16x16x32_bf16(paf_, VF[1][cc], o[s][1], 0, 0, 0); \
            o[s][2] = __builtin_amdgcn_mfma_f32_16x16x32_bf16(paf_, VF[2][cc], o[s][2], 0, 0, 0); \
            o[s][3] = __builtin_amdgcn_mfma_f32_16x16x32_bf16(paf_, VF[3][cc], o[s][3], 0, 0, 0); \
            __builtin_amdgcn_s_setprio(0);                                    \
        }                                                                     \
    }                                                                         \
}

template<int CHUNK>
__global__ __launch_bounds__(64, 2) void attn_part(
    const unsigned short* __restrict__ Qb,
    const unsigned short* __restrict__ Kb,
    const unsigned short* __restrict__ Vt,
    unsigned short* __restrict__ po, float* __restrict__ pml)
{
    constexpr int NCH = 64 / CHUNK;
    const int idx  = blockIdx.x;
    const int c    = idx >> 9;                    // chunk layer
    const int b    = idx & 3;
    const int ti32 = 127 - ((idx >> 2) & 127);    // heavy-first
    const int nkt  = (ti32 >> 1) + 1;
    const int kt0  = c * CHUNK;
    if (kt0 >= nkt) return;
    const int ntile = min(nkt - kt0, CHUNK);

    const int l  = threadIdx.x;
    const int lr = l & 15, g = l >> 4;
    const int q0 = ti32 * 32;
    const size_t bTT = (size_t)b * TT;

    // Q fragments (B-operand): lane holds Q[q0+s*16+lr][k=g*8..+7]
    bfrag qa[2][2];
#pragma unroll
    for (int s = 0; s < 2; ++s) {
        const size_t qr = (bTT + q0 + s * 16 + lr) * 64 + g * 8;
        qa[s][0] = *(const bfrag*)&Qb[qr];
        qa[s][1] = *(const bfrag*)&Qb[qr + 32];
    }

    // hoisted base pointers (elements)
    const unsigned short* kp0 = Kb + (bTT + (size_t)kt0 * 64 + lr) * 64 + g * 8;
    const unsigned short* vp0 = Vt + ((size_t)b * 64 + lr) * TT + (size_t)kt0 * 64 + g * 8;

    // bpermute lane addresses (bytes): w2<2 -> lane lr+32*(g&1); w2>=2 -> +16
    const int addr_a = (lr + 32 * (g & 1)) * 4;
    const int addr_b = addr_a + 64;
    const bool ghi = (g >= 2);

    f32x4 o[2][4];
#pragma unroll
    for (int s = 0; s < 2; ++s)
#pragma unroll
        for (int ht = 0; ht < 4; ++ht) o[s][ht] = (f32x4){0.f, 0.f, 0.f, 0.f};
    float mrow[2] = {-1e30f, -1e30f};
    float lrow[2] = {0.f, 0.f};

    // double-buffered K frags; V single-buffered (latency hides under softmax)
    bfrag kfA[4][2], kfB[4][2], vf[4][2];
    LOADK(kfA, 0);

#pragma unroll
    for (int t = 0; t < CHUNK; t += 2) {
        if (t >= ntile) break;
        LOADV(vf, t);
        if (t + 1 < ntile) LOADK(kfB, t + 1);
        COMPUTE(kfA, vf, t);
        if (t + 1 >= ntile) break;
        LOADV(vf, t + 1);
        if (t + 2 < ntile) LOADK(kfA, t + 2);
        COMPUTE(kfB, vf, t + 1);
    }

    // store partials: po coded C-layout bf16 (coalesced), pml (m,l) f32
    const int slot = (((b << 7) + ti32) * NCH) + c;
    const size_t pob = (size_t)slot * 2048;
#pragma unroll
    for (int s = 0; s < 2; ++s)
#pragma unroll
        for (int ht = 0; ht < 4; ++ht)
#pragma unroll
            for (int rg = 0; rg < 4; ++rg)
                po[pob + (size_t)(((s * 4 + ht) * 4 + rg) * 64 + l)] = f2bf(o[s][ht][rg]);
    if (g == 0) {
#pragma unroll
        for (int s = 0; s < 2; ++s) {
            pml[slot * 64 + s * 16 + lr]      = mrow[s];
            pml[slot * 64 + 32 + s * 16 + lr] = lrow[s];
        }
    }
}

// ---------------------------------------------------------------------------
// Merge split-K partials. ROUND 12: 2x parallelism — grid = 1024 (two blocks
// per (b, ti32)), 256 threads, 4 coded elements each (ushort4 loads).
// ---------------------------------------------------------------------------
__global__ __launch_bounds__(256) void attn_merge(
    const unsigned short* __restrict__ po, const float* __restrict__ pml,
    float* __restrict__ out, int chunk, int nch)
{
    const int idx  = blockIdx.x >> 1;  // 0..511: (b, ti32)
    const int half = blockIdx.x & 1;
    const int b    = idx & 3;
    const int ti32 = idx >> 2;
    const int nkt  = (ti32 >> 1) + 1;
    const int nc   = (nkt + chunk - 1) / chunk;

    const int e0   = half * 1024 + threadIdx.x * 4;
    const int lane = e0 & 63;
    const int rg   = (e0 >> 6) & 3;
    const int ht   = (e0 >> 8) & 3;
    const int s    = e0 >> 10;
    const int row  = s * 16 + ((lane >> 4) << 2) + rg;
    const int col0 = ht * 16 + (lane & 15);
    const int slot0 = ((b << 7) + ti32) * nch;

    float M = -1e30f;
    for (int c = 0; c < nc; ++c)
        M = fmaxf(M, pml[(slot0 + c) * 64 + row]);

    float den = 0.f;
    float acc[4];
#pragma unroll
    for (int i = 0; i < 4; ++i) acc[i] = 0.f;

    for (int c = 0; c < nc; ++c) {
        const float wgt = exp2f(pml[(slot0 + c) * 64 + row] - M);
        den += wgt * pml[(slot0 + c) * 64 + 32 + row];
        const ushort4t v = *(const ushort4t*)&po[(size_t)(slot0 + c) * 2048 + e0];
#pragma unroll
        for (int j = 0; j < 4; ++j) acc[j] += wgt * bf2f(v[j]);
    }
    const float inv = 1.0f / den;
    float* dst = out + ((size_t)b * TT + ti32 * 32 + row) * 64 + col0;
    float4 o0 = {acc[0] * inv, acc[1] * inv, acc[2] * inv, acc[3] * inv};
    *(float4*)(dst) = o0;
}

// ---------------------------------------------------------------------------
extern "C" void kernel_launch(void* const* d_in, const int* in_sizes, int n_in,
                              void* d_out, int out_size, void* d_ws, size_t ws_size,
                              hipStream_t stream)
{
    const float* emb = (const float*)d_in[0];
    const float* Wk  = (const float*)d_in[1];
    const float* bk  = (const float*)d_in[2];
    const float* Wq  = (const float*)d_in[3];
    const float* bq  = (const float*)d_in[4];
    const float* Wv  = (const float*)d_in[5];
    const float* bv  = (const float*)d_in[6];
    float* out = (float*)d_out;

    // ws: Qb[2MB] Kb[2MB] Vt[2MB] Wt[384KB] | po (bf16) | pml (f32)
    char* base = (char*)d_ws;
    unsigned short* Qb = (unsigned short*)(base);
    unsigned short* Kb = (unsigned short*)(base + (2u << 20));
    unsigned short* Vt = (unsigned short*)(base + (4u << 20));
    unsigned short* Wt = (unsigned short*)(base + (6u << 20));
    const size_t pbase = ((size_t)6 << 20) + (512u << 10);   // 6.5 MB

    // split-K ladder: nch=16 (42.2MB) if it fits, else nch=8 (24.3MB)
    int nch = 16;
    {
        const size_t need16 = pbase +
            (size_t)512 * 16 * (2048 * sizeof(unsigned short) + 64 * sizeof(float));
        if (need16 > ws_size) nch = 8;
    }
    const int chunk = 64 / nch;
    unsigned short* po = (unsigned short*)(base + pbase);
    float* pml = (float*)(po + (size_t)512 * nch * 2048);

    prep_wt<<<192 * 1024 / 256, 256, 0, stream>>>(Wk, Wq, Wv, Wt);
    qkv_mfma<<<(NB * TT) / 64, 256, 0, stream>>>(emb, Wt, bk, bq, bv, Qb, Kb, Vt);
    if (nch == 16)
        attn_part<4><<<512 * 16, 64, 0, stream>>>(Qb, Kb, Vt, po, pml);
    else
        attn_part<8><<<512 * 8, 64, 0, stream>>>(Qb, Kb, Vt, po, pml);
    attn_merge<<<1024, 256, 0, stream>>>(po, pml, out, chunk, nch);
}